// Round 3
// baseline (614.172 us; speedup 1.0000x reference)
//
#include <hip/hip_runtime.h>

#define N_NODES 100000
#define N_EDGES 3200000
#define BN_EPS 1e-5f
#define SCAN_BLOCKS 391   // ceil(100000/256)

// workspace layout (4-byte units)
constexpr int O_STATS = 0;                      // 8 f
constexpr int O_CNT   = 8;                      // N int
constexpr int O_OFFS  = O_CNT + N_NODES;        // N int
constexpr int O_BSUM  = O_OFFS + N_NODES;       // 512 int
constexpr int O_RANK  = O_BSUM + 512;           // E int
constexpr int O_H     = O_RANK + N_EDGES;       // N*4 f
constexpr int O_H2    = O_H + 4 * N_NODES;      // N*2 f
constexpr int O_MSG   = O_H2 + 2 * N_NODES;     // E*4 f (conv1: float2[E], conv2: float4[E])

__global__ void bn_stats_kernel(const float* __restrict__ x, float* __restrict__ stats) {
    int i = blockIdx.x * blockDim.x + threadIdx.x;
    float s0=0.f,s1=0.f,s2=0.f,s3=0.f,q0=0.f,q1=0.f,q2=0.f,q3=0.f;
    if (i < N_NODES) {
        float4 v = reinterpret_cast<const float4*>(x)[i];
        s0=v.x; s1=v.y; s2=v.z; s3=v.w;
        q0=v.x*v.x; q1=v.y*v.y; q2=v.z*v.z; q3=v.w*v.w;
    }
    #pragma unroll
    for (int off = 32; off > 0; off >>= 1) {
        s0 += __shfl_down(s0, off); s1 += __shfl_down(s1, off);
        s2 += __shfl_down(s2, off); s3 += __shfl_down(s3, off);
        q0 += __shfl_down(q0, off); q1 += __shfl_down(q1, off);
        q2 += __shfl_down(q2, off); q3 += __shfl_down(q3, off);
    }
    if ((threadIdx.x & 63) == 0) {
        atomicAdd(&stats[0], s0); atomicAdd(&stats[1], s1);
        atomicAdd(&stats[2], s2); atomicAdd(&stats[3], s3);
        atomicAdd(&stats[4], q0); atomicAdd(&stats[5], q1);
        atomicAdd(&stats[6], q2); atomicAdd(&stats[7], q3);
    }
}

__global__ void bn_apply_kernel(const float* __restrict__ x,
                                const float* __restrict__ stats,
                                const float* __restrict__ gamma,
                                const float* __restrict__ beta,
                                float* __restrict__ h) {
    int i = blockIdx.x * blockDim.x + threadIdx.x;
    if (i >= N_NODES) return;
    const float inv_n = 1.0f / (float)N_NODES;
    float m0 = stats[0]*inv_n, m1 = stats[1]*inv_n, m2 = stats[2]*inv_n, m3 = stats[3]*inv_n;
    float sc0 = rsqrtf(stats[4]*inv_n - m0*m0 + BN_EPS) * gamma[0];
    float sc1 = rsqrtf(stats[5]*inv_n - m1*m1 + BN_EPS) * gamma[1];
    float sc2 = rsqrtf(stats[6]*inv_n - m2*m2 + BN_EPS) * gamma[2];
    float sc3 = rsqrtf(stats[7]*inv_n - m3*m3 + BN_EPS) * gamma[3];
    float4 v = reinterpret_cast<const float4*>(x)[i];
    float4 o;
    o.x = (v.x - m0) * sc0 + beta[0];
    o.y = (v.y - m1) * sc1 + beta[1];
    o.z = (v.z - m2) * sc2 + beta[2];
    o.w = (v.w - m3) * sc3 + beta[3];
    reinterpret_cast<float4*>(h)[i] = o;
}

// rank[e] = arrival index among edges sharing dst; cnt[d] = in-degree
__global__ void rank_kernel(const int* __restrict__ ei, int* __restrict__ cnt,
                            int* __restrict__ rank) {
    int e = blockIdx.x * 256 + threadIdx.x;
    if (e >= N_EDGES) return;
    int d = ei[N_EDGES + e];
    rank[e] = atomicAdd(&cnt[d], 1);
}

__global__ void scan_block_kernel(const int* __restrict__ cnt, int* __restrict__ offs,
                                  int* __restrict__ bsums) {
    __shared__ int sd[256];
    int t = threadIdx.x;
    int i = blockIdx.x * 256 + t;
    int v = (i < N_NODES) ? cnt[i] : 0;
    sd[t] = v; __syncthreads();
    for (int o = 1; o < 256; o <<= 1) {
        int x = (t >= o) ? sd[t - o] : 0;
        __syncthreads();
        sd[t] += x;
        __syncthreads();
    }
    if (i < N_NODES) offs[i] = sd[t] - v;           // exclusive within block
    if (t == 255) bsums[blockIdx.x] = sd[255];
}

__global__ void scan_mid_kernel(int* __restrict__ bsums) {
    __shared__ int sd[512];
    int t = threadIdx.x;
    int v = (t < SCAN_BLOCKS) ? bsums[t] : 0;
    sd[t] = v; __syncthreads();
    for (int o = 1; o < 512; o <<= 1) {
        int x = (t >= o) ? sd[t - o] : 0;
        __syncthreads();
        sd[t] += x;
        __syncthreads();
    }
    if (t < SCAN_BLOCKS) bsums[t] = sd[t] - v;      // exclusive block offsets
}

__global__ void scan_add_kernel(int* __restrict__ offs, const int* __restrict__ bsums) {
    int i = blockIdx.x * 256 + threadIdx.x;
    if (i < N_NODES) offs[i] += bsums[blockIdx.x];
}

__global__ __launch_bounds__(256, 4) void conv1_edge_kernel(
    const float* __restrict__ h, const int* __restrict__ ei,
    const int* __restrict__ rank, const int* __restrict__ offs,
    const float* __restrict__ w1, const float* __restrict__ b1,
    const float* __restrict__ w2, const float* __restrict__ b2,
    const float* __restrict__ w3, const float* __restrict__ b3,
    float* __restrict__ msg)   // float2[E], sorted by dst
{
    __shared__ float W1s[256], B1s[32], W2s[1024], B2s[32], W3s[64], B3s[2];
    for (int t = threadIdx.x; t < 256; t += 256) W1s[t] = w1[t];
    for (int t = threadIdx.x; t < 1024; t += 256) W2s[t] = w2[t];
    if (threadIdx.x < 32) { B1s[threadIdx.x] = b1[threadIdx.x]; B2s[threadIdx.x] = b2[threadIdx.x]; }
    if (threadIdx.x < 64) W3s[threadIdx.x] = w3[threadIdx.x];
    if (threadIdx.x < 2)  B3s[threadIdx.x] = b3[threadIdx.x];
    __syncthreads();

    int e = blockIdx.x * 256 + threadIdx.x;
    if (e >= N_EDGES) return;
    int s = ei[e];
    int d = ei[N_EDGES + e];
    float4 xi = reinterpret_cast<const float4*>(h)[d];
    float4 xj = reinterpret_cast<const float4*>(h)[s];
    float in[8] = {xi.x, xi.y, xi.z, xi.w,
                   xj.x - xi.x, xj.y - xi.y, xj.z - xi.z, xj.w - xi.w};
    float a1[32];
    #pragma unroll
    for (int j = 0; j < 32; j++) a1[j] = B1s[j];
    #pragma unroll
    for (int k = 0; k < 8; k++) {
        float v = in[k];
        #pragma unroll
        for (int j = 0; j < 32; j++) a1[j] = fmaf(v, W1s[k*32 + j], a1[j]);
    }
    #pragma unroll
    for (int j = 0; j < 32; j++) a1[j] = fmaxf(a1[j], 0.f);

    float a2[32];
    #pragma unroll
    for (int j = 0; j < 32; j++) a2[j] = B2s[j];
    #pragma unroll
    for (int k = 0; k < 32; k++) {
        float v = a1[k];
        #pragma unroll
        for (int j = 0; j < 32; j++) a2[j] = fmaf(v, W2s[k*32 + j], a2[j]);
    }
    #pragma unroll
    for (int j = 0; j < 32; j++) a2[j] = fmaxf(a2[j], 0.f);

    float m0 = B3s[0], m1 = B3s[1];
    #pragma unroll
    for (int k = 0; k < 32; k++) {
        m0 = fmaf(a2[k], W3s[2*k],     m0);
        m1 = fmaf(a2[k], W3s[2*k + 1], m1);
    }
    m0 = fmaxf(m0, 0.f); m1 = fmaxf(m1, 0.f);

    int pos = offs[d] + rank[e];
    reinterpret_cast<float2*>(msg)[pos] = make_float2(m0, m1);
}

// mean over contiguous segment; 32 lanes per node, 2 nodes per wave
__global__ void agg1_kernel(const float* __restrict__ msg, const int* __restrict__ offs,
                            const int* __restrict__ cnt, float* __restrict__ h2) {
    int lane = threadIdx.x & 63;
    int wave = threadIdx.x >> 6;
    int node = blockIdx.x * 8 + wave * 2 + (lane >> 5);
    int sub = lane & 31;
    if (node >= N_NODES) return;
    int base = offs[node];
    int deg  = cnt[node];
    float s0 = 0.f, s1 = 0.f;
    for (int k = sub; k < deg; k += 32) {
        float2 m = reinterpret_cast<const float2*>(msg)[base + k];
        s0 += m.x; s1 += m.y;
    }
    #pragma unroll
    for (int o = 16; o > 0; o >>= 1) {
        s0 += __shfl_down(s0, o, 32);
        s1 += __shfl_down(s1, o, 32);
    }
    if (sub == 0) {
        float c = fmaxf((float)deg, 1.f);
        reinterpret_cast<float2*>(h2)[node] = make_float2(s0 / c, s1 / c);
    }
}

__global__ __launch_bounds__(256, 4) void conv2_edge_kernel(
    const float* __restrict__ h2, const int* __restrict__ ei,
    const int* __restrict__ rank, const int* __restrict__ offs,
    const float* __restrict__ w1, const float* __restrict__ b1,
    const float* __restrict__ w2, const float* __restrict__ b2,
    const float* __restrict__ w3, const float* __restrict__ b3,
    float* __restrict__ msg)   // float4[E], sorted by dst
{
    __shared__ float W1s[128], B1s[32], W2s[1024], B2s[32], W3s[128], B3s[4];
    for (int t = threadIdx.x; t < 128; t += 256) W1s[t] = w1[t];
    for (int t = threadIdx.x; t < 1024; t += 256) W2s[t] = w2[t];
    if (threadIdx.x < 32) { B1s[threadIdx.x] = b1[threadIdx.x]; B2s[threadIdx.x] = b2[threadIdx.x]; }
    if (threadIdx.x < 128) W3s[threadIdx.x] = w3[threadIdx.x];
    if (threadIdx.x < 4)   B3s[threadIdx.x] = b3[threadIdx.x];
    __syncthreads();

    int e = blockIdx.x * 256 + threadIdx.x;
    if (e >= N_EDGES) return;
    int s = ei[e];
    int d = ei[N_EDGES + e];
    float2 yi = reinterpret_cast<const float2*>(h2)[d];
    float2 yj = reinterpret_cast<const float2*>(h2)[s];
    float in[4] = {yi.x, yi.y, yj.x - yi.x, yj.y - yi.y};

    float a1[32];
    #pragma unroll
    for (int j = 0; j < 32; j++) a1[j] = B1s[j];
    #pragma unroll
    for (int k = 0; k < 4; k++) {
        float v = in[k];
        #pragma unroll
        for (int j = 0; j < 32; j++) a1[j] = fmaf(v, W1s[k*32 + j], a1[j]);
    }
    #pragma unroll
    for (int j = 0; j < 32; j++) a1[j] = fmaxf(a1[j], 0.f);

    float a2[32];
    #pragma unroll
    for (int j = 0; j < 32; j++) a2[j] = B2s[j];
    #pragma unroll
    for (int k = 0; k < 32; k++) {
        float v = a1[k];
        #pragma unroll
        for (int j = 0; j < 32; j++) a2[j] = fmaf(v, W2s[k*32 + j], a2[j]);
    }
    #pragma unroll
    for (int j = 0; j < 32; j++) a2[j] = fmaxf(a2[j], 0.f);

    float o0 = B3s[0], o1 = B3s[1], o2 = B3s[2], o3 = B3s[3];
    #pragma unroll
    for (int k = 0; k < 32; k++) {
        float v = a2[k];
        o0 = fmaf(v, W3s[4*k],     o0);
        o1 = fmaf(v, W3s[4*k + 1], o1);
        o2 = fmaf(v, W3s[4*k + 2], o2);
        o3 = fmaf(v, W3s[4*k + 3], o3);
    }
    int pos = offs[d] + rank[e];
    reinterpret_cast<float4*>(msg)[pos] = make_float4(o0, o1, o2, o3);
}

__global__ void agg2_kernel(const float* __restrict__ msg, const int* __restrict__ offs,
                            const int* __restrict__ cnt, float* __restrict__ out) {
    int lane = threadIdx.x & 63;
    int wave = threadIdx.x >> 6;
    int node = blockIdx.x * 8 + wave * 2 + (lane >> 5);
    int sub = lane & 31;
    if (node >= N_NODES) return;
    int base = offs[node];
    int deg  = cnt[node];
    float s0 = 0.f, s1 = 0.f, s2 = 0.f, s3 = 0.f;
    for (int k = sub; k < deg; k += 32) {
        float4 m = reinterpret_cast<const float4*>(msg)[base + k];
        s0 += m.x; s1 += m.y; s2 += m.z; s3 += m.w;
    }
    #pragma unroll
    for (int o = 16; o > 0; o >>= 1) {
        s0 += __shfl_down(s0, o, 32); s1 += __shfl_down(s1, o, 32);
        s2 += __shfl_down(s2, o, 32); s3 += __shfl_down(s3, o, 32);
    }
    if (sub == 0) {
        float c = fmaxf((float)deg, 1.f);
        reinterpret_cast<float4*>(out)[node] = make_float4(s0/c, s1/c, s2/c, s3/c);
    }
}

extern "C" void kernel_launch(void* const* d_in, const int* in_sizes, int n_in,
                              void* d_out, int out_size, void* d_ws, size_t ws_size,
                              hipStream_t stream) {
    const float* x        = (const float*)d_in[0];
    const int*   ei       = (const int*)  d_in[1];
    const float* bn_gamma = (const float*)d_in[2];
    const float* bn_beta  = (const float*)d_in[3];
    const float* enc_w1   = (const float*)d_in[4];
    const float* enc_b1   = (const float*)d_in[5];
    const float* enc_w2   = (const float*)d_in[6];
    const float* enc_b2   = (const float*)d_in[7];
    const float* enc_w3   = (const float*)d_in[8];
    const float* enc_b3   = (const float*)d_in[9];
    const float* dec_w1   = (const float*)d_in[10];
    const float* dec_b1   = (const float*)d_in[11];
    const float* dec_w2   = (const float*)d_in[12];
    const float* dec_b2   = (const float*)d_in[13];
    const float* dec_w3   = (const float*)d_in[14];
    const float* dec_b3   = (const float*)d_in[15];

    float* wsf   = (float*)d_ws;
    int*   wsi   = (int*)d_ws;
    float* stats = wsf + O_STATS;
    int*   cnt   = wsi + O_CNT;
    int*   offs  = wsi + O_OFFS;
    int*   bsums = wsi + O_BSUM;
    int*   rank  = wsi + O_RANK;
    float* h     = wsf + O_H;
    float* h2    = wsf + O_H2;
    float* msg   = wsf + O_MSG;
    float* out   = (float*)d_out;

    // zero stats (8 f) + cnt (N int) — contiguous
    hipMemsetAsync(d_ws, 0, (size_t)(8 + N_NODES) * sizeof(float), stream);

    const int nodeBlocks = (N_NODES + 255) / 256;
    const int edgeBlocks = (N_EDGES + 255) / 256;
    const int aggBlocks  = (N_NODES + 7) / 8;

    bn_stats_kernel<<<nodeBlocks, 256, 0, stream>>>(x, stats);
    bn_apply_kernel<<<nodeBlocks, 256, 0, stream>>>(x, stats, bn_gamma, bn_beta, h);
    rank_kernel<<<edgeBlocks, 256, 0, stream>>>(ei, cnt, rank);
    scan_block_kernel<<<SCAN_BLOCKS, 256, 0, stream>>>(cnt, offs, bsums);
    scan_mid_kernel<<<1, 512, 0, stream>>>(bsums);
    scan_add_kernel<<<SCAN_BLOCKS, 256, 0, stream>>>(offs, bsums);
    conv1_edge_kernel<<<edgeBlocks, 256, 0, stream>>>(h, ei, rank, offs,
                                                      enc_w1, enc_b1, enc_w2, enc_b2,
                                                      enc_w3, enc_b3, msg);
    agg1_kernel<<<aggBlocks, 256, 0, stream>>>(msg, offs, cnt, h2);
    conv2_edge_kernel<<<edgeBlocks, 256, 0, stream>>>(h2, ei, rank, offs,
                                                      dec_w1, dec_b1, dec_w2, dec_b2,
                                                      dec_w3, dec_b3, msg);
    agg2_kernel<<<aggBlocks, 256, 0, stream>>>(msg, offs, cnt, out);
}

// Round 4
// 586.401 us; speedup vs baseline: 1.0474x; 1.0474x over previous
//
#include <hip/hip_runtime.h>

#define N_NODES 100000
#define N_EDGES 3200000
#define BN_EPS 1e-5f
#define SCAN_BLOCKS 391   // ceil(100000/256)

// workspace layout (4-byte units)
constexpr int O_STATS = 0;                      // 8 f
constexpr int O_CNT   = 8;                      // N int
constexpr int O_OFFS  = O_CNT + N_NODES;        // N int
constexpr int O_BSUM  = O_OFFS + N_NODES;       // 512 int
constexpr int O_RANK  = O_BSUM + 512;           // E int
constexpr int O_H     = O_RANK + N_EDGES;       // N*4 f
constexpr int O_H2    = O_H + 4 * N_NODES;      // N*2 f
constexpr int O_MSG   = O_H2 + 2 * N_NODES;     // E*4 f (conv1: float2[E], conv2: float4[E])

__global__ void bn_stats_kernel(const float* __restrict__ x, float* __restrict__ stats) {
    int i = blockIdx.x * blockDim.x + threadIdx.x;
    float s0=0.f,s1=0.f,s2=0.f,s3=0.f,q0=0.f,q1=0.f,q2=0.f,q3=0.f;
    if (i < N_NODES) {
        float4 v = reinterpret_cast<const float4*>(x)[i];
        s0=v.x; s1=v.y; s2=v.z; s3=v.w;
        q0=v.x*v.x; q1=v.y*v.y; q2=v.z*v.z; q3=v.w*v.w;
    }
    #pragma unroll
    for (int off = 32; off > 0; off >>= 1) {
        s0 += __shfl_down(s0, off); s1 += __shfl_down(s1, off);
        s2 += __shfl_down(s2, off); s3 += __shfl_down(s3, off);
        q0 += __shfl_down(q0, off); q1 += __shfl_down(q1, off);
        q2 += __shfl_down(q2, off); q3 += __shfl_down(q3, off);
    }
    if ((threadIdx.x & 63) == 0) {
        atomicAdd(&stats[0], s0); atomicAdd(&stats[1], s1);
        atomicAdd(&stats[2], s2); atomicAdd(&stats[3], s3);
        atomicAdd(&stats[4], q0); atomicAdd(&stats[5], q1);
        atomicAdd(&stats[6], q2); atomicAdd(&stats[7], q3);
    }
}

__global__ void bn_apply_kernel(const float* __restrict__ x,
                                const float* __restrict__ stats,
                                const float* __restrict__ gamma,
                                const float* __restrict__ beta,
                                float* __restrict__ h) {
    int i = blockIdx.x * blockDim.x + threadIdx.x;
    if (i >= N_NODES) return;
    const float inv_n = 1.0f / (float)N_NODES;
    float m0 = stats[0]*inv_n, m1 = stats[1]*inv_n, m2 = stats[2]*inv_n, m3 = stats[3]*inv_n;
    float sc0 = rsqrtf(stats[4]*inv_n - m0*m0 + BN_EPS) * gamma[0];
    float sc1 = rsqrtf(stats[5]*inv_n - m1*m1 + BN_EPS) * gamma[1];
    float sc2 = rsqrtf(stats[6]*inv_n - m2*m2 + BN_EPS) * gamma[2];
    float sc3 = rsqrtf(stats[7]*inv_n - m3*m3 + BN_EPS) * gamma[3];
    float4 v = reinterpret_cast<const float4*>(x)[i];
    float4 o;
    o.x = (v.x - m0) * sc0 + beta[0];
    o.y = (v.y - m1) * sc1 + beta[1];
    o.z = (v.z - m2) * sc2 + beta[2];
    o.w = (v.w - m3) * sc3 + beta[3];
    reinterpret_cast<float4*>(h)[i] = o;
}

// rank[e] = arrival index among edges sharing dst; cnt[d] = in-degree
__global__ void rank_kernel(const int* __restrict__ ei, int* __restrict__ cnt,
                            int* __restrict__ rank) {
    int e = blockIdx.x * 256 + threadIdx.x;
    if (e >= N_EDGES) return;
    int d = ei[N_EDGES + e];
    rank[e] = atomicAdd(&cnt[d], 1);
}

__global__ void scan_block_kernel(const int* __restrict__ cnt, int* __restrict__ offs,
                                  int* __restrict__ bsums) {
    __shared__ int sd[256];
    int t = threadIdx.x;
    int i = blockIdx.x * 256 + t;
    int v = (i < N_NODES) ? cnt[i] : 0;
    sd[t] = v; __syncthreads();
    for (int o = 1; o < 256; o <<= 1) {
        int x = (t >= o) ? sd[t - o] : 0;
        __syncthreads();
        sd[t] += x;
        __syncthreads();
    }
    if (i < N_NODES) offs[i] = sd[t] - v;           // exclusive within block
    if (t == 255) bsums[blockIdx.x] = sd[255];
}

__global__ void scan_mid_kernel(int* __restrict__ bsums) {
    __shared__ int sd[512];
    int t = threadIdx.x;
    int v = (t < SCAN_BLOCKS) ? bsums[t] : 0;
    sd[t] = v; __syncthreads();
    for (int o = 1; o < 512; o <<= 1) {
        int x = (t >= o) ? sd[t - o] : 0;
        __syncthreads();
        sd[t] += x;
        __syncthreads();
    }
    if (t < SCAN_BLOCKS) bsums[t] = sd[t] - v;      // exclusive block offsets
}

__global__ void scan_add_kernel(int* __restrict__ offs, const int* __restrict__ bsums) {
    int i = blockIdx.x * 256 + threadIdx.x;
    if (i < N_NODES) offs[i] += bsums[blockIdx.x];
}

__global__ __launch_bounds__(256, 4) void conv1_edge_kernel(
    const float* __restrict__ h, const int* __restrict__ ei,
    const int* __restrict__ rank, const int* __restrict__ offs,
    const float* __restrict__ w1, const float* __restrict__ b1,
    const float* __restrict__ w2, const float* __restrict__ b2,
    const float* __restrict__ w3, const float* __restrict__ b3,
    float* __restrict__ msg)   // float2[E], sorted by dst
{
    int e = blockIdx.x * 256 + threadIdx.x;
    if (e >= N_EDGES) return;
    int s = ei[e];
    int d = ei[N_EDGES + e];
    int pos = offs[d] + rank[e];             // issue early, overlaps MLP
    float4 xi = reinterpret_cast<const float4*>(h)[d];
    float4 xj = reinterpret_cast<const float4*>(h)[s];
    float in[8] = {xi.x, xi.y, xi.z, xi.w,
                   xj.x - xi.x, xj.y - xi.y, xj.z - xi.z, xj.w - xi.w};
    // weights read with wave-uniform, compile-time indices -> s_load path
    float a1[32];
    #pragma unroll
    for (int j = 0; j < 32; j++) a1[j] = b1[j];
    #pragma unroll
    for (int k = 0; k < 8; k++) {
        float v = in[k];
        #pragma unroll
        for (int j = 0; j < 32; j++) a1[j] = fmaf(v, w1[k*32 + j], a1[j]);
    }
    #pragma unroll
    for (int j = 0; j < 32; j++) a1[j] = fmaxf(a1[j], 0.f);

    float a2[32];
    #pragma unroll
    for (int j = 0; j < 32; j++) a2[j] = b2[j];
    #pragma unroll
    for (int k = 0; k < 32; k++) {
        float v = a1[k];
        #pragma unroll
        for (int j = 0; j < 32; j++) a2[j] = fmaf(v, w2[k*32 + j], a2[j]);
    }
    #pragma unroll
    for (int j = 0; j < 32; j++) a2[j] = fmaxf(a2[j], 0.f);

    float m0 = b3[0], m1 = b3[1];
    #pragma unroll
    for (int k = 0; k < 32; k++) {
        m0 = fmaf(a2[k], w3[2*k],     m0);
        m1 = fmaf(a2[k], w3[2*k + 1], m1);
    }
    m0 = fmaxf(m0, 0.f); m1 = fmaxf(m1, 0.f);

    reinterpret_cast<float2*>(msg)[pos] = make_float2(m0, m1);
}

// mean over contiguous segment; 32 lanes per node, 2 nodes per wave
__global__ void agg1_kernel(const float* __restrict__ msg, const int* __restrict__ offs,
                            const int* __restrict__ cnt, float* __restrict__ h2) {
    int lane = threadIdx.x & 63;
    int wave = threadIdx.x >> 6;
    int node = blockIdx.x * 8 + wave * 2 + (lane >> 5);
    int sub = lane & 31;
    if (node >= N_NODES) return;
    int base = offs[node];
    int deg  = cnt[node];
    float s0 = 0.f, s1 = 0.f;
    for (int k = sub; k < deg; k += 32) {
        float2 m = reinterpret_cast<const float2*>(msg)[base + k];
        s0 += m.x; s1 += m.y;
    }
    #pragma unroll
    for (int o = 16; o > 0; o >>= 1) {
        s0 += __shfl_down(s0, o, 32);
        s1 += __shfl_down(s1, o, 32);
    }
    if (sub == 0) {
        float c = fmaxf((float)deg, 1.f);
        reinterpret_cast<float2*>(h2)[node] = make_float2(s0 / c, s1 / c);
    }
}

__global__ __launch_bounds__(256, 4) void conv2_edge_kernel(
    const float* __restrict__ h2, const int* __restrict__ ei,
    const int* __restrict__ rank, const int* __restrict__ offs,
    const float* __restrict__ w1, const float* __restrict__ b1,
    const float* __restrict__ w2, const float* __restrict__ b2,
    const float* __restrict__ w3, const float* __restrict__ b3,
    float* __restrict__ msg)   // float4[E], sorted by dst
{
    int e = blockIdx.x * 256 + threadIdx.x;
    if (e >= N_EDGES) return;
    int s = ei[e];
    int d = ei[N_EDGES + e];
    int pos = offs[d] + rank[e];
    float2 yi = reinterpret_cast<const float2*>(h2)[d];
    float2 yj = reinterpret_cast<const float2*>(h2)[s];
    float in[4] = {yi.x, yi.y, yj.x - yi.x, yj.y - yi.y};

    float a1[32];
    #pragma unroll
    for (int j = 0; j < 32; j++) a1[j] = b1[j];
    #pragma unroll
    for (int k = 0; k < 4; k++) {
        float v = in[k];
        #pragma unroll
        for (int j = 0; j < 32; j++) a1[j] = fmaf(v, w1[k*32 + j], a1[j]);
    }
    #pragma unroll
    for (int j = 0; j < 32; j++) a1[j] = fmaxf(a1[j], 0.f);

    float a2[32];
    #pragma unroll
    for (int j = 0; j < 32; j++) a2[j] = b2[j];
    #pragma unroll
    for (int k = 0; k < 32; k++) {
        float v = a1[k];
        #pragma unroll
        for (int j = 0; j < 32; j++) a2[j] = fmaf(v, w2[k*32 + j], a2[j]);
    }
    #pragma unroll
    for (int j = 0; j < 32; j++) a2[j] = fmaxf(a2[j], 0.f);

    float o0 = b3[0], o1 = b3[1], o2 = b3[2], o3 = b3[3];
    #pragma unroll
    for (int k = 0; k < 32; k++) {
        float v = a2[k];
        o0 = fmaf(v, w3[4*k],     o0);
        o1 = fmaf(v, w3[4*k + 1], o1);
        o2 = fmaf(v, w3[4*k + 2], o2);
        o3 = fmaf(v, w3[4*k + 3], o3);
    }
    reinterpret_cast<float4*>(msg)[pos] = make_float4(o0, o1, o2, o3);
}

__global__ void agg2_kernel(const float* __restrict__ msg, const int* __restrict__ offs,
                            const int* __restrict__ cnt, float* __restrict__ out) {
    int lane = threadIdx.x & 63;
    int wave = threadIdx.x >> 6;
    int node = blockIdx.x * 8 + wave * 2 + (lane >> 5);
    int sub = lane & 31;
    if (node >= N_NODES) return;
    int base = offs[node];
    int deg  = cnt[node];
    float s0 = 0.f, s1 = 0.f, s2 = 0.f, s3 = 0.f;
    for (int k = sub; k < deg; k += 32) {
        float4 m = reinterpret_cast<const float4*>(msg)[base + k];
        s0 += m.x; s1 += m.y; s2 += m.z; s3 += m.w;
    }
    #pragma unroll
    for (int o = 16; o > 0; o >>= 1) {
        s0 += __shfl_down(s0, o, 32); s1 += __shfl_down(s1, o, 32);
        s2 += __shfl_down(s2, o, 32); s3 += __shfl_down(s3, o, 32);
    }
    if (sub == 0) {
        float c = fmaxf((float)deg, 1.f);
        reinterpret_cast<float4*>(out)[node] = make_float4(s0/c, s1/c, s2/c, s3/c);
    }
}

extern "C" void kernel_launch(void* const* d_in, const int* in_sizes, int n_in,
                              void* d_out, int out_size, void* d_ws, size_t ws_size,
                              hipStream_t stream) {
    const float* x        = (const float*)d_in[0];
    const int*   ei       = (const int*)  d_in[1];
    const float* bn_gamma = (const float*)d_in[2];
    const float* bn_beta  = (const float*)d_in[3];
    const float* enc_w1   = (const float*)d_in[4];
    const float* enc_b1   = (const float*)d_in[5];
    const float* enc_w2   = (const float*)d_in[6];
    const float* enc_b2   = (const float*)d_in[7];
    const float* enc_w3   = (const float*)d_in[8];
    const float* enc_b3   = (const float*)d_in[9];
    const float* dec_w1   = (const float*)d_in[10];
    const float* dec_b1   = (const float*)d_in[11];
    const float* dec_w2   = (const float*)d_in[12];
    const float* dec_b2   = (const float*)d_in[13];
    const float* dec_w3   = (const float*)d_in[14];
    const float* dec_b3   = (const float*)d_in[15];

    float* wsf   = (float*)d_ws;
    int*   wsi   = (int*)d_ws;
    float* stats = wsf + O_STATS;
    int*   cnt   = wsi + O_CNT;
    int*   offs  = wsi + O_OFFS;
    int*   bsums = wsi + O_BSUM;
    int*   rank  = wsi + O_RANK;
    float* h     = wsf + O_H;
    float* h2    = wsf + O_H2;
    float* msg   = wsf + O_MSG;
    float* out   = (float*)d_out;

    // zero stats (8 f) + cnt (N int) — contiguous
    hipMemsetAsync(d_ws, 0, (size_t)(8 + N_NODES) * sizeof(float), stream);

    const int nodeBlocks = (N_NODES + 255) / 256;
    const int edgeBlocks = (N_EDGES + 255) / 256;
    const int aggBlocks  = (N_NODES + 7) / 8;

    bn_stats_kernel<<<nodeBlocks, 256, 0, stream>>>(x, stats);
    bn_apply_kernel<<<nodeBlocks, 256, 0, stream>>>(x, stats, bn_gamma, bn_beta, h);
    rank_kernel<<<edgeBlocks, 256, 0, stream>>>(ei, cnt, rank);
    scan_block_kernel<<<SCAN_BLOCKS, 256, 0, stream>>>(cnt, offs, bsums);
    scan_mid_kernel<<<1, 512, 0, stream>>>(bsums);
    scan_add_kernel<<<SCAN_BLOCKS, 256, 0, stream>>>(offs, bsums);
    conv1_edge_kernel<<<edgeBlocks, 256, 0, stream>>>(h, ei, rank, offs,
                                                      enc_w1, enc_b1, enc_w2, enc_b2,
                                                      enc_w3, enc_b3, msg);
    agg1_kernel<<<aggBlocks, 256, 0, stream>>>(msg, offs, cnt, h2);
    conv2_edge_kernel<<<edgeBlocks, 256, 0, stream>>>(h2, ei, rank, offs,
                                                      dec_w1, dec_b1, dec_w2, dec_b2,
                                                      dec_w3, dec_b3, msg);
    agg2_kernel<<<aggBlocks, 256, 0, stream>>>(msg, offs, cnt, out);
}

// Round 5
// 430.251 us; speedup vs baseline: 1.4275x; 1.3629x over previous
//
#include <hip/hip_runtime.h>

#define N_NODES 100000
#define N_EDGES 3200000
#define BN_EPS 1e-5f
#define SCAN_BLOCKS 391   // ceil(100000/256)
#define STATS_BLOCKS 64

// workspace layout (4-byte units)
constexpr int O_STATS = 0;                      // 8 f
constexpr int O_CNT   = 8;                      // N int
constexpr int O_OFFS  = O_CNT + N_NODES;        // N int
constexpr int O_BSUM  = O_OFFS + N_NODES;       // 512 int
constexpr int O_RANK  = O_BSUM + 512;           // E int
constexpr int O_H     = O_RANK + N_EDGES;       // N*4 f
constexpr int O_H2    = O_H + 4 * N_NODES;      // N*2 f
constexpr int O_MSG   = O_H2 + 2 * N_NODES;     // E*4 f (conv1: float2[E], conv2: float4[E])

__global__ __launch_bounds__(256) void bn_stats_kernel(const float* __restrict__ x,
                                                       float* __restrict__ stats) {
    __shared__ float red[4][8];
    int tid = threadIdx.x;
    float s0=0.f,s1=0.f,s2=0.f,s3=0.f,q0=0.f,q1=0.f,q2=0.f,q3=0.f;
    for (int i = blockIdx.x * 256 + tid; i < N_NODES; i += STATS_BLOCKS * 256) {
        float4 v = reinterpret_cast<const float4*>(x)[i];
        s0+=v.x; s1+=v.y; s2+=v.z; s3+=v.w;
        q0=fmaf(v.x,v.x,q0); q1=fmaf(v.y,v.y,q1); q2=fmaf(v.z,v.z,q2); q3=fmaf(v.w,v.w,q3);
    }
    #pragma unroll
    for (int off = 32; off > 0; off >>= 1) {
        s0 += __shfl_down(s0, off); s1 += __shfl_down(s1, off);
        s2 += __shfl_down(s2, off); s3 += __shfl_down(s3, off);
        q0 += __shfl_down(q0, off); q1 += __shfl_down(q1, off);
        q2 += __shfl_down(q2, off); q3 += __shfl_down(q3, off);
    }
    int wave = tid >> 6, lane = tid & 63;
    if (lane == 0) {
        red[wave][0]=s0; red[wave][1]=s1; red[wave][2]=s2; red[wave][3]=s3;
        red[wave][4]=q0; red[wave][5]=q1; red[wave][6]=q2; red[wave][7]=q3;
    }
    __syncthreads();
    if (tid < 8) {
        float v = red[0][tid] + red[1][tid] + red[2][tid] + red[3][tid];
        atomicAdd(&stats[tid], v);
    }
}

__global__ void bn_apply_kernel(const float* __restrict__ x,
                                const float* __restrict__ stats,
                                const float* __restrict__ gamma,
                                const float* __restrict__ beta,
                                float* __restrict__ h) {
    int i = blockIdx.x * blockDim.x + threadIdx.x;
    if (i >= N_NODES) return;
    const float inv_n = 1.0f / (float)N_NODES;
    float m0 = stats[0]*inv_n, m1 = stats[1]*inv_n, m2 = stats[2]*inv_n, m3 = stats[3]*inv_n;
    float sc0 = rsqrtf(stats[4]*inv_n - m0*m0 + BN_EPS) * gamma[0];
    float sc1 = rsqrtf(stats[5]*inv_n - m1*m1 + BN_EPS) * gamma[1];
    float sc2 = rsqrtf(stats[6]*inv_n - m2*m2 + BN_EPS) * gamma[2];
    float sc3 = rsqrtf(stats[7]*inv_n - m3*m3 + BN_EPS) * gamma[3];
    float4 v = reinterpret_cast<const float4*>(x)[i];
    float4 o;
    o.x = (v.x - m0) * sc0 + beta[0];
    o.y = (v.y - m1) * sc1 + beta[1];
    o.z = (v.z - m2) * sc2 + beta[2];
    o.w = (v.w - m3) * sc3 + beta[3];
    reinterpret_cast<float4*>(h)[i] = o;
}

// rank[e] = arrival index among edges sharing dst; cnt[d] = in-degree
__global__ void rank_kernel(const int* __restrict__ ei, int* __restrict__ cnt,
                            int* __restrict__ rank) {
    int e = blockIdx.x * 256 + threadIdx.x;
    if (e >= N_EDGES) return;
    int d = ei[N_EDGES + e];
    rank[e] = atomicAdd(&cnt[d], 1);
}

__global__ void scan_block_kernel(const int* __restrict__ cnt, int* __restrict__ offs,
                                  int* __restrict__ bsums) {
    __shared__ int sd[256];
    int t = threadIdx.x;
    int i = blockIdx.x * 256 + t;
    int v = (i < N_NODES) ? cnt[i] : 0;
    sd[t] = v; __syncthreads();
    for (int o = 1; o < 256; o <<= 1) {
        int x = (t >= o) ? sd[t - o] : 0;
        __syncthreads();
        sd[t] += x;
        __syncthreads();
    }
    if (i < N_NODES) offs[i] = sd[t] - v;           // exclusive within block
    if (t == 255) bsums[blockIdx.x] = sd[255];
}

__global__ void scan_mid_kernel(int* __restrict__ bsums) {
    __shared__ int sd[512];
    int t = threadIdx.x;
    int v = (t < SCAN_BLOCKS) ? bsums[t] : 0;
    sd[t] = v; __syncthreads();
    for (int o = 1; o < 512; o <<= 1) {
        int x = (t >= o) ? sd[t - o] : 0;
        __syncthreads();
        sd[t] += x;
        __syncthreads();
    }
    if (t < SCAN_BLOCKS) bsums[t] = sd[t] - v;      // exclusive block offsets
}

__global__ void scan_add_kernel(int* __restrict__ offs, const int* __restrict__ bsums) {
    int i = blockIdx.x * 256 + threadIdx.x;
    if (i < N_NODES) offs[i] += bsums[blockIdx.x];
}

__global__ __launch_bounds__(256, 4) void conv1_edge_kernel(
    const float* __restrict__ h, const int* __restrict__ ei,
    const int* __restrict__ rank, const int* __restrict__ offs,
    const float* __restrict__ w1, const float* __restrict__ b1,
    const float* __restrict__ w2, const float* __restrict__ b2,
    const float* __restrict__ w3, const float* __restrict__ b3,
    float* __restrict__ msg)   // float2[E], sorted by dst
{
    int e = blockIdx.x * 256 + threadIdx.x;
    if (e >= N_EDGES) return;
    int s = ei[e];
    int d = ei[N_EDGES + e];
    int pos = offs[d] + rank[e];             // issue early, overlaps MLP
    float4 xi = reinterpret_cast<const float4*>(h)[d];
    float4 xj = reinterpret_cast<const float4*>(h)[s];
    float in[8] = {xi.x, xi.y, xi.z, xi.w,
                   xj.x - xi.x, xj.y - xi.y, xj.z - xi.z, xj.w - xi.w};
    // weights read with wave-uniform, compile-time indices -> s_load path
    float a1[32];
    #pragma unroll
    for (int j = 0; j < 32; j++) a1[j] = b1[j];
    #pragma unroll
    for (int k = 0; k < 8; k++) {
        float v = in[k];
        #pragma unroll
        for (int j = 0; j < 32; j++) a1[j] = fmaf(v, w1[k*32 + j], a1[j]);
    }
    #pragma unroll
    for (int j = 0; j < 32; j++) a1[j] = fmaxf(a1[j], 0.f);

    float a2[32];
    #pragma unroll
    for (int j = 0; j < 32; j++) a2[j] = b2[j];
    #pragma unroll
    for (int k = 0; k < 32; k++) {
        float v = a1[k];
        #pragma unroll
        for (int j = 0; j < 32; j++) a2[j] = fmaf(v, w2[k*32 + j], a2[j]);
    }
    #pragma unroll
    for (int j = 0; j < 32; j++) a2[j] = fmaxf(a2[j], 0.f);

    float m0 = b3[0], m1 = b3[1];
    #pragma unroll
    for (int k = 0; k < 32; k++) {
        m0 = fmaf(a2[k], w3[2*k],     m0);
        m1 = fmaf(a2[k], w3[2*k + 1], m1);
    }
    m0 = fmaxf(m0, 0.f); m1 = fmaxf(m1, 0.f);

    reinterpret_cast<float2*>(msg)[pos] = make_float2(m0, m1);
}

// mean over contiguous segment; 32 lanes per node, 2 nodes per wave
__global__ void agg1_kernel(const float* __restrict__ msg, const int* __restrict__ offs,
                            const int* __restrict__ cnt, float* __restrict__ h2) {
    int lane = threadIdx.x & 63;
    int wave = threadIdx.x >> 6;
    int node = blockIdx.x * 8 + wave * 2 + (lane >> 5);
    int sub = lane & 31;
    if (node >= N_NODES) return;
    int base = offs[node];
    int deg  = cnt[node];
    float s0 = 0.f, s1 = 0.f;
    for (int k = sub; k < deg; k += 32) {
        float2 m = reinterpret_cast<const float2*>(msg)[base + k];
        s0 += m.x; s1 += m.y;
    }
    #pragma unroll
    for (int o = 16; o > 0; o >>= 1) {
        s0 += __shfl_down(s0, o, 32);
        s1 += __shfl_down(s1, o, 32);
    }
    if (sub == 0) {
        float c = fmaxf((float)deg, 1.f);
        reinterpret_cast<float2*>(h2)[node] = make_float2(s0 / c, s1 / c);
    }
}

__global__ __launch_bounds__(256, 4) void conv2_edge_kernel(
    const float* __restrict__ h2, const int* __restrict__ ei,
    const int* __restrict__ rank, const int* __restrict__ offs,
    const float* __restrict__ w1, const float* __restrict__ b1,
    const float* __restrict__ w2, const float* __restrict__ b2,
    const float* __restrict__ w3, const float* __restrict__ b3,
    float* __restrict__ msg)   // float4[E], sorted by dst
{
    int e = blockIdx.x * 256 + threadIdx.x;
    if (e >= N_EDGES) return;
    int s = ei[e];
    int d = ei[N_EDGES + e];
    int pos = offs[d] + rank[e];
    float2 yi = reinterpret_cast<const float2*>(h2)[d];
    float2 yj = reinterpret_cast<const float2*>(h2)[s];
    float in[4] = {yi.x, yi.y, yj.x - yi.x, yj.y - yi.y};

    float a1[32];
    #pragma unroll
    for (int j = 0; j < 32; j++) a1[j] = b1[j];
    #pragma unroll
    for (int k = 0; k < 4; k++) {
        float v = in[k];
        #pragma unroll
        for (int j = 0; j < 32; j++) a1[j] = fmaf(v, w1[k*32 + j], a1[j]);
    }
    #pragma unroll
    for (int j = 0; j < 32; j++) a1[j] = fmaxf(a1[j], 0.f);

    float a2[32];
    #pragma unroll
    for (int j = 0; j < 32; j++) a2[j] = b2[j];
    #pragma unroll
    for (int k = 0; k < 32; k++) {
        float v = a1[k];
        #pragma unroll
        for (int j = 0; j < 32; j++) a2[j] = fmaf(v, w2[k*32 + j], a2[j]);
    }
    #pragma unroll
    for (int j = 0; j < 32; j++) a2[j] = fmaxf(a2[j], 0.f);

    float o0 = b3[0], o1 = b3[1], o2 = b3[2], o3 = b3[3];
    #pragma unroll
    for (int k = 0; k < 32; k++) {
        float v = a2[k];
        o0 = fmaf(v, w3[4*k],     o0);
        o1 = fmaf(v, w3[4*k + 1], o1);
        o2 = fmaf(v, w3[4*k + 2], o2);
        o3 = fmaf(v, w3[4*k + 3], o3);
    }
    reinterpret_cast<float4*>(msg)[pos] = make_float4(o0, o1, o2, o3);
}

__global__ void agg2_kernel(const float* __restrict__ msg, const int* __restrict__ offs,
                            const int* __restrict__ cnt, float* __restrict__ out) {
    int lane = threadIdx.x & 63;
    int wave = threadIdx.x >> 6;
    int node = blockIdx.x * 8 + wave * 2 + (lane >> 5);
    int sub = lane & 31;
    if (node >= N_NODES) return;
    int base = offs[node];
    int deg  = cnt[node];
    float s0 = 0.f, s1 = 0.f, s2 = 0.f, s3 = 0.f;
    for (int k = sub; k < deg; k += 32) {
        float4 m = reinterpret_cast<const float4*>(msg)[base + k];
        s0 += m.x; s1 += m.y; s2 += m.z; s3 += m.w;
    }
    #pragma unroll
    for (int o = 16; o > 0; o >>= 1) {
        s0 += __shfl_down(s0, o, 32); s1 += __shfl_down(s1, o, 32);
        s2 += __shfl_down(s2, o, 32); s3 += __shfl_down(s3, o, 32);
    }
    if (sub == 0) {
        float c = fmaxf((float)deg, 1.f);
        reinterpret_cast<float4*>(out)[node] = make_float4(s0/c, s1/c, s2/c, s3/c);
    }
}

extern "C" void kernel_launch(void* const* d_in, const int* in_sizes, int n_in,
                              void* d_out, int out_size, void* d_ws, size_t ws_size,
                              hipStream_t stream) {
    const float* x        = (const float*)d_in[0];
    const int*   ei       = (const int*)  d_in[1];
    const float* bn_gamma = (const float*)d_in[2];
    const float* bn_beta  = (const float*)d_in[3];
    const float* enc_w1   = (const float*)d_in[4];
    const float* enc_b1   = (const float*)d_in[5];
    const float* enc_w2   = (const float*)d_in[6];
    const float* enc_b2   = (const float*)d_in[7];
    const float* enc_w3   = (const float*)d_in[8];
    const float* enc_b3   = (const float*)d_in[9];
    const float* dec_w1   = (const float*)d_in[10];
    const float* dec_b1   = (const float*)d_in[11];
    const float* dec_w2   = (const float*)d_in[12];
    const float* dec_b2   = (const float*)d_in[13];
    const float* dec_w3   = (const float*)d_in[14];
    const float* dec_b3   = (const float*)d_in[15];

    float* wsf   = (float*)d_ws;
    int*   wsi   = (int*)d_ws;
    float* stats = wsf + O_STATS;
    int*   cnt   = wsi + O_CNT;
    int*   offs  = wsi + O_OFFS;
    int*   bsums = wsi + O_BSUM;
    int*   rank  = wsi + O_RANK;
    float* h     = wsf + O_H;
    float* h2    = wsf + O_H2;
    float* msg   = wsf + O_MSG;
    float* out   = (float*)d_out;

    // zero stats (8 f) + cnt (N int) — contiguous
    hipMemsetAsync(d_ws, 0, (size_t)(8 + N_NODES) * sizeof(float), stream);

    const int nodeBlocks = (N_NODES + 255) / 256;
    const int edgeBlocks = (N_EDGES + 255) / 256;
    const int aggBlocks  = (N_NODES + 7) / 8;

    bn_stats_kernel<<<STATS_BLOCKS, 256, 0, stream>>>(x, stats);
    bn_apply_kernel<<<nodeBlocks, 256, 0, stream>>>(x, stats, bn_gamma, bn_beta, h);
    rank_kernel<<<edgeBlocks, 256, 0, stream>>>(ei, cnt, rank);
    scan_block_kernel<<<SCAN_BLOCKS, 256, 0, stream>>>(cnt, offs, bsums);
    scan_mid_kernel<<<1, 512, 0, stream>>>(bsums);
    scan_add_kernel<<<SCAN_BLOCKS, 256, 0, stream>>>(offs, bsums);
    conv1_edge_kernel<<<edgeBlocks, 256, 0, stream>>>(h, ei, rank, offs,
                                                      enc_w1, enc_b1, enc_w2, enc_b2,
                                                      enc_w3, enc_b3, msg);
    agg1_kernel<<<aggBlocks, 256, 0, stream>>>(msg, offs, cnt, h2);
    conv2_edge_kernel<<<edgeBlocks, 256, 0, stream>>>(h2, ei, rank, offs,
                                                      dec_w1, dec_b1, dec_w2, dec_b2,
                                                      dec_w3, dec_b3, msg);
    agg2_kernel<<<aggBlocks, 256, 0, stream>>>(msg, offs, cnt, out);
}